// Round 4
// baseline (317.506 us; speedup 1.0000x reference)
//
#include <hip/hip_runtime.h>

#define BF_STAGES 10
#define BF_DIM 1024
#define BF_R 4   // rows per wave: amortizes table loads 4x, 4-way ILP

typedef float f32x4 __attribute__((ext_vector_type(4)));

// Pre-kernel: cs[s*512+k] = (cos(angles[s][k]), sin(angles[s][k])), 40 KB in d_ws.
__global__ void bf_fill_cs(const float* __restrict__ angles, float2* __restrict__ cs, int n) {
    int i = blockIdx.x * blockDim.x + threadIdx.x;
    if (i < n) {
        float a = angles[i];
        float s, c;
        sincosf(a, &s, &c);
        cs[i] = make_float2(c, s);
    }
}

// In-place rotate of a register pair.
#define ROT(vi, vj, c, s) do { float _t = (c)*(vi) - (s)*(vj); (vj) = (s)*(vi) + (c)*(vj); (vi) = _t; } while (0)

// Lane-exchange partner value for xor-mask MSK.
// MSK 1,2 -> DPP quad_perm (VALU pipe, no LDS). MSK 4..32 -> ds_swizzle/bpermute.
template <int MSK>
__device__ __forceinline__ float bf_partner(float x) {
    if constexpr (MSK == 1) {
        // quad_perm [1,0,3,2] = 1 | (0<<2) | (3<<4) | (2<<6) = 0xB1
        return __int_as_float(__builtin_amdgcn_update_dpp(0, __float_as_int(x), 0xB1, 0xF, 0xF, true));
    } else if constexpr (MSK == 2) {
        // quad_perm [2,3,0,1] = 2 | (3<<2) | (0<<4) | (1<<6) = 0x4E
        return __int_as_float(__builtin_amdgcn_update_dpp(0, __float_as_int(x), 0x4E, 0xF, 0xF, true));
    } else {
        return __shfl_xor(x, MSK);
    }
}

// Cross-lane stage S (2..7): lane-bit b = S-2, partner lane = lane ^ (1<<b).
// Angle index k = element index with bit S deleted; per-mh tables cA (m_lo 0,1), cB (m_lo 2,3).
// Sign sg folded into the shuffled value (1 v_mul) instead of 16 pre-folded regs:
// register pressure is the scarce resource here, VALU is at 14%.
template <int S>
__device__ __forceinline__ void bf_cross_stage(f32x4 (&v)[BF_R][4], const f32x4* __restrict__ csf4,
                                               int lane) {
    constexpr int b   = S - 2;
    constexpr int msk = 1 << b;
    const int lc = ((lane >> (b + 1)) << b) | (lane & (msk - 1)); // lane with bit b deleted
    const float sg = (lane & msk) ? 1.0f : -1.0f;                 // j-side: +s, i-side: -s
    f32x4 cA[4], cB[4];
#pragma unroll
    for (int mh = 0; mh < 4; ++mh) {
        cA[mh] = csf4[S * 256 + mh * 64 + lc * 2];
        cB[mh] = csf4[S * 256 + mh * 64 + lc * 2 + 1];
    }
#pragma unroll
    for (int r = 0; r < BF_R; ++r) {
#pragma unroll
        for (int mh = 0; mh < 4; ++mh) {
            f32x4 w;
            w.x = sg * bf_partner<msk>(v[r][mh].x);
            w.y = sg * bf_partner<msk>(v[r][mh].y);
            w.z = sg * bf_partner<msk>(v[r][mh].z);
            w.w = sg * bf_partner<msk>(v[r][mh].w);
            // v' = c*v + sg*s*w   (i-side: c*vi - s*vj ; j-side: s*vi + c*vj)
            v[r][mh].x = fmaf(cA[mh].y, w.x, cA[mh].x * v[r][mh].x);
            v[r][mh].y = fmaf(cA[mh].w, w.y, cA[mh].z * v[r][mh].y);
            v[r][mh].z = fmaf(cB[mh].y, w.z, cB[mh].x * v[r][mh].z);
            v[r][mh].w = fmaf(cB[mh].w, w.w, cB[mh].z * v[r][mh].w);
        }
    }
}

// One wave == BF_R consecutive rows of 1024 floats, held entirely in registers.
// Element mapping: e = m_hi*256 + lane*4 + m_lo   (m_hi, m_lo in 0..3, lane in 0..63)
//   stage 0,1  -> bits 0,1 of e  -> intra-float4
//   stage 2..7 -> lane bits 0..5 -> lane exchange, mask 1<<(s-2)
//   stage 8,9  -> bits 8,9 of e  -> across the four float4s
// Angle index for stage s: k = e with bit s deleted.
// csf4 view: csf4[s*256 + k/2] = (cos[k], sin[k], cos[k+1], sin[k+1]).
// amdgpu_waves_per_eu(4,4): pin exactly 4 waves/SIMD -> 128-VGPR budget. With a
// plain __launch_bounds__ minimum the allocator chased 8 waves/EU (64 VGPRs)
// and spilled ~400 MB to scratch (round-3 counters).
__global__ __launch_bounds__(256)
__attribute__((amdgpu_waves_per_eu(4, 4)))
void bf_butterfly(const float* __restrict__ x,
                  const f32x4* __restrict__ csf4,
                  float* __restrict__ out,
                  int n_rows) {
    const int lane = threadIdx.x & 63;
    const int wv   = threadIdx.x >> 6;
    const long long row0 = ((long long)blockIdx.x * 4 + wv) * BF_R;
    if (row0 >= n_rows) return;

    const float* xr  = x   + row0 * BF_DIM;
    float*       orr = out + row0 * BF_DIM;

    f32x4 v[BF_R][4];
#pragma unroll
    for (int r = 0; r < BF_R; ++r) {
        if (row0 + r < n_rows) {
#pragma unroll
            for (int mh = 0; mh < 4; ++mh)
                v[r][mh] = __builtin_nontemporal_load(
                    reinterpret_cast<const f32x4*>(xr + r * BF_DIM + mh * 256 + lane * 4));
        } else {
#pragma unroll
            for (int mh = 0; mh < 4; ++mh)
                v[r][mh] = (f32x4){0.f, 0.f, 0.f, 0.f};
        }
    }

    // ---- stage 0: pairs (x,y) and (z,w); k = mh*128 + lane*2 + {0,1}
    {
        f32x4 c[4];
#pragma unroll
        for (int mh = 0; mh < 4; ++mh) c[mh] = csf4[0 * 256 + mh * 64 + lane];
#pragma unroll
        for (int r = 0; r < BF_R; ++r)
#pragma unroll
            for (int mh = 0; mh < 4; ++mh) {
                ROT(v[r][mh].x, v[r][mh].y, c[mh].x, c[mh].y);
                ROT(v[r][mh].z, v[r][mh].w, c[mh].z, c[mh].w);
            }
    }
    // ---- stage 1: pairs (x,z) and (y,w); same k addresses, stage-1 table
    {
        f32x4 c[4];
#pragma unroll
        for (int mh = 0; mh < 4; ++mh) c[mh] = csf4[1 * 256 + mh * 64 + lane];
#pragma unroll
        for (int r = 0; r < BF_R; ++r)
#pragma unroll
            for (int mh = 0; mh < 4; ++mh) {
                ROT(v[r][mh].x, v[r][mh].z, c[mh].x, c[mh].y);
                ROT(v[r][mh].y, v[r][mh].w, c[mh].z, c[mh].w);
            }
    }

    // ---- stages 2..7: cross-lane
    bf_cross_stage<2>(v, csf4, lane);
    bf_cross_stage<3>(v, csf4, lane);
    bf_cross_stage<4>(v, csf4, lane);
    bf_cross_stage<5>(v, csf4, lane);
    bf_cross_stage<6>(v, csf4, lane);
    bf_cross_stage<7>(v, csf4, lane);

    // ---- stage 8: pairs (v[0],v[1]) k=lane*4+mlo ; (v[2],v[3]) k=256+lane*4+mlo
    {
        f32x4 a0 = csf4[8 * 256 + lane * 2];
        f32x4 a1 = csf4[8 * 256 + lane * 2 + 1];
        f32x4 b0 = csf4[8 * 256 + 128 + lane * 2];
        f32x4 b1 = csf4[8 * 256 + 128 + lane * 2 + 1];
#pragma unroll
        for (int r = 0; r < BF_R; ++r) {
            ROT(v[r][0].x, v[r][1].x, a0.x, a0.y);
            ROT(v[r][0].y, v[r][1].y, a0.z, a0.w);
            ROT(v[r][0].z, v[r][1].z, a1.x, a1.y);
            ROT(v[r][0].w, v[r][1].w, a1.z, a1.w);
            ROT(v[r][2].x, v[r][3].x, b0.x, b0.y);
            ROT(v[r][2].y, v[r][3].y, b0.z, b0.w);
            ROT(v[r][2].z, v[r][3].z, b1.x, b1.y);
            ROT(v[r][2].w, v[r][3].w, b1.z, b1.w);
        }
    }
    // ---- stage 9: pairs (v[0],v[2]) k=lane*4+mlo ; (v[1],v[3]) k=256+lane*4+mlo
    {
        f32x4 a0 = csf4[9 * 256 + lane * 2];
        f32x4 a1 = csf4[9 * 256 + lane * 2 + 1];
        f32x4 b0 = csf4[9 * 256 + 128 + lane * 2];
        f32x4 b1 = csf4[9 * 256 + 128 + lane * 2 + 1];
#pragma unroll
        for (int r = 0; r < BF_R; ++r) {
            ROT(v[r][0].x, v[r][2].x, a0.x, a0.y);
            ROT(v[r][0].y, v[r][2].y, a0.z, a0.w);
            ROT(v[r][0].z, v[r][2].z, a1.x, a1.y);
            ROT(v[r][0].w, v[r][2].w, a1.z, a1.w);
            ROT(v[r][1].x, v[r][3].x, b0.x, b0.y);
            ROT(v[r][1].y, v[r][3].y, b0.z, b0.w);
            ROT(v[r][1].z, v[r][3].z, b1.x, b1.y);
            ROT(v[r][1].w, v[r][3].w, b1.z, b1.w);
        }
    }

#pragma unroll
    for (int r = 0; r < BF_R; ++r) {
        if (row0 + r < n_rows) {
#pragma unroll
            for (int mh = 0; mh < 4; ++mh)
                __builtin_nontemporal_store(
                    v[r][mh], reinterpret_cast<f32x4*>(orr + r * BF_DIM + mh * 256 + lane * 4));
        }
    }
}

extern "C" void kernel_launch(void* const* d_in, const int* in_sizes, int n_in,
                              void* d_out, int out_size, void* d_ws, size_t ws_size,
                              hipStream_t stream) {
    const float* x      = (const float*)d_in[0];
    const float* angles = (const float*)d_in[1];
    float*       out    = (float*)d_out;
    float2*      cs     = (float2*)d_ws;   // 10*512*8 = 40960 bytes

    const int ncs = BF_STAGES * (BF_DIM / 2);
    bf_fill_cs<<<(ncs + 255) / 256, 256, 0, stream>>>(angles, cs, ncs);

    const int rows   = in_sizes[0] / BF_DIM;
    const int waves  = (rows + BF_R - 1) / BF_R;
    const int blocks = (waves + 3) / 4;   // 4 waves per 256-thread block
    bf_butterfly<<<blocks, 256, 0, stream>>>(x, (const f32x4*)cs, out, rows);
}

// Round 5
// 239.193 us; speedup vs baseline: 1.3274x; 1.3274x over previous
//
#include <hip/hip_runtime.h>

typedef float f32x4 __attribute__((ext_vector_type(4)));

#define BF_DIM 1024
#define BF_STAGES 10

// Tables: cs[s*512 + pos] = (cos, sin) of angles[s][k].
// Stages 0-3, 8, 9: pos = k (natural).
// Stages 4-7: permuted so each lane's 8 needed entries are contiguous:
//   k = hi2*128 + j*16 + lo4  ->  pos = (hi2*16 + lo4)*8 + j
__global__ void bf_fill_cs(const float* __restrict__ angles, float2* __restrict__ cs, int n) {
    int i = blockIdx.x * blockDim.x + threadIdx.x;
    if (i >= n) return;
    int s = i >> 9, k = i & 511;
    float a = angles[i];
    float sv, cv;
    sincosf(a, &sv, &cv);
    int pos;
    if (s >= 4 && s < 8) {
        int hi2 = k >> 7, j = (k >> 4) & 7, lo4 = k & 15;
        pos = ((hi2 << 4) | lo4) * 8 + j;
    } else {
        pos = k;
    }
    cs[s * 512 + pos] = make_float2(cv, sv);
}

#define ROT(vi, vj, c, s) do { float _t = fmaf(-(s), (vj), (c)*(vi)); \
                               (vj) = fmaf((s), (vi), (c)*(vj)); (vi) = _t; } while (0)

// Four recurring butterfly patterns on a quad of f32x4 (A0..A3) with 4 table vecs.
// EVEN_INNER: pairs (x,y),(z,w) inside each vec           (stage 0 / 4)
#define STAGE_EVEN_INNER(A0,A1,A2,A3,c0,c1,c2,c3) do { \
    ROT(A0.x,A0.y,c0.x,c0.y); ROT(A0.z,A0.w,c0.z,c0.w); \
    ROT(A1.x,A1.y,c1.x,c1.y); ROT(A1.z,A1.w,c1.z,c1.w); \
    ROT(A2.x,A2.y,c2.x,c2.y); ROT(A2.z,A2.w,c2.z,c2.w); \
    ROT(A3.x,A3.y,c3.x,c3.y); ROT(A3.z,A3.w,c3.z,c3.w); } while (0)
// ODD_INNER: pairs (x,z),(y,w) inside each vec            (stage 1 / 5)
#define STAGE_ODD_INNER(A0,A1,A2,A3,c0,c1,c2,c3) do { \
    ROT(A0.x,A0.z,c0.x,c0.y); ROT(A0.y,A0.w,c0.z,c0.w); \
    ROT(A1.x,A1.z,c1.x,c1.y); ROT(A1.y,A1.w,c1.z,c1.w); \
    ROT(A2.x,A2.z,c2.x,c2.y); ROT(A2.y,A2.w,c2.z,c2.w); \
    ROT(A3.x,A3.z,c3.x,c3.y); ROT(A3.y,A3.w,c3.z,c3.w); } while (0)
// PAIR01: (A0,A1) componentwise with c0,c1; (A2,A3) with c2,c3   (stage 2 / 6)
#define STAGE_PAIR01(A0,A1,A2,A3,c0,c1,c2,c3) do { \
    ROT(A0.x,A1.x,c0.x,c0.y); ROT(A0.y,A1.y,c0.z,c0.w); \
    ROT(A0.z,A1.z,c1.x,c1.y); ROT(A0.w,A1.w,c1.z,c1.w); \
    ROT(A2.x,A3.x,c2.x,c2.y); ROT(A2.y,A3.y,c2.z,c2.w); \
    ROT(A2.z,A3.z,c3.x,c3.y); ROT(A2.w,A3.w,c3.z,c3.w); } while (0)
// PAIR02: (A0,A2) with c0,c1; (A1,A3) with c2,c3                 (stage 3 / 7)
#define STAGE_PAIR02(A0,A1,A2,A3,c0,c1,c2,c3) do { \
    ROT(A0.x,A2.x,c0.x,c0.y); ROT(A0.y,A2.y,c0.z,c0.w); \
    ROT(A0.z,A2.z,c1.x,c1.y); ROT(A0.w,A2.w,c1.z,c1.w); \
    ROT(A1.x,A3.x,c2.x,c2.y); ROT(A1.y,A3.y,c2.z,c2.w); \
    ROT(A1.z,A3.z,c3.x,c3.y); ROT(A1.w,A3.w,c3.z,c3.w); } while (0)

// One wave = one row of 1024 floats, 16 per thread, zero cross-lane shuffles.
//  Layout A: lane holds e = lane*16 + q*4 + c (contiguous)  -> stages 0-3 in regs
//  LDS transpose 1 (padded word stride 20)                  -> stages 4-7 in regs
//  LDS transpose 2                                          -> stages 8-9 in regs, coalesced store
// Element lives at LDS word W(e) = (e>>4)*20 + (e&15); pad breaks power-of-2 strides.
__global__ __launch_bounds__(256) void bf_butterfly(const float* __restrict__ x,
                                                    const f32x4* __restrict__ T,
                                                    float* __restrict__ out,
                                                    int n_rows) {
    __shared__ __align__(16) float lds[4 * 1280];  // 4 waves * 64 lanes * 20 words = 20 KB
    const int lane = threadIdx.x & 63;
    const int wv   = threadIdx.x >> 6;
    int row = blockIdx.x * 4 + wv;
    if (row >= n_rows) row = n_rows - 1;  // duplicate tail work; keeps barriers uniform
    const float* xr  = x   + (long long)row * BF_DIM;
    float*       orr = out + (long long)row * BF_DIM;
    float*       L   = lds + wv * 1280;

    // ---- load, layout A (contiguous 64B per lane)
    f32x4 U0 = __builtin_nontemporal_load((const f32x4*)(xr + lane * 16 + 0));
    f32x4 U1 = __builtin_nontemporal_load((const f32x4*)(xr + lane * 16 + 4));
    f32x4 U2 = __builtin_nontemporal_load((const f32x4*)(xr + lane * 16 + 8));
    f32x4 U3 = __builtin_nontemporal_load((const f32x4*)(xr + lane * 16 + 12));

    const int ta = lane * 4;  // f32x4 index of this lane's 64B table slice
    {   // stage 0
        f32x4 c0 = T[ta], c1 = T[ta + 1], c2 = T[ta + 2], c3 = T[ta + 3];
        STAGE_EVEN_INNER(U0, U1, U2, U3, c0, c1, c2, c3);
    }
    {   // stage 1
        f32x4 c0 = T[256 + ta], c1 = T[256 + ta + 1], c2 = T[256 + ta + 2], c3 = T[256 + ta + 3];
        STAGE_ODD_INNER(U0, U1, U2, U3, c0, c1, c2, c3);
    }
    {   // stage 2
        f32x4 c0 = T[512 + ta], c1 = T[512 + ta + 1], c2 = T[512 + ta + 2], c3 = T[512 + ta + 3];
        STAGE_PAIR01(U0, U1, U2, U3, c0, c1, c2, c3);
    }
    {   // stage 3
        f32x4 c0 = T[768 + ta], c1 = T[768 + ta + 1], c2 = T[768 + ta + 2], c3 = T[768 + ta + 3];
        STAGE_PAIR02(U0, U1, U2, U3, c0, c1, c2, c3);
    }

    // ---- transpose 1: write A (b128, 8-way-optimal banks), read B (b32, 4-way)
    {
        const int wb = lane * 20;
        *(f32x4*)(L + wb + 0)  = U0;
        *(f32x4*)(L + wb + 4)  = U1;
        *(f32x4*)(L + wb + 8)  = U2;
        *(f32x4*)(L + wb + 12) = U3;
    }
    __syncthreads();
    const int rb = (lane >> 4) * 320 + (lane & 15);  // layout B/C base: (b98*16)*20 + lo4
    f32x4 B0, B1, B2, B3;
    B0.x = L[rb + 0 * 20];  B0.y = L[rb + 1 * 20];  B0.z = L[rb + 2 * 20];  B0.w = L[rb + 3 * 20];
    B1.x = L[rb + 4 * 20];  B1.y = L[rb + 5 * 20];  B1.z = L[rb + 6 * 20];  B1.w = L[rb + 7 * 20];
    B2.x = L[rb + 8 * 20];  B2.y = L[rb + 9 * 20];  B2.z = L[rb + 10 * 20]; B2.w = L[rb + 11 * 20];
    B3.x = L[rb + 12 * 20]; B3.y = L[rb + 13 * 20]; B3.z = L[rb + 14 * 20]; B3.w = L[rb + 15 * 20];

    {   // stage 4
        f32x4 c0 = T[1024 + ta], c1 = T[1024 + ta + 1], c2 = T[1024 + ta + 2], c3 = T[1024 + ta + 3];
        STAGE_EVEN_INNER(B0, B1, B2, B3, c0, c1, c2, c3);
    }
    {   // stage 5
        f32x4 c0 = T[1280 + ta], c1 = T[1280 + ta + 1], c2 = T[1280 + ta + 2], c3 = T[1280 + ta + 3];
        STAGE_ODD_INNER(B0, B1, B2, B3, c0, c1, c2, c3);
    }
    {   // stage 6
        f32x4 c0 = T[1536 + ta], c1 = T[1536 + ta + 1], c2 = T[1536 + ta + 2], c3 = T[1536 + ta + 3];
        STAGE_PAIR01(B0, B1, B2, B3, c0, c1, c2, c3);
    }
    {   // stage 7
        f32x4 c0 = T[1792 + ta], c1 = T[1792 + ta + 1], c2 = T[1792 + ta + 2], c3 = T[1792 + ta + 3];
        STAGE_PAIR02(B0, B1, B2, B3, c0, c1, c2, c3);
    }

    // ---- transpose 2: write B back at W(e) (b32), read C (b128, 8-way-optimal)
    __syncthreads();  // WAR: don't overwrite words other lanes are still reading
    L[rb + 0 * 20]  = B0.x; L[rb + 1 * 20]  = B0.y; L[rb + 2 * 20]  = B0.z; L[rb + 3 * 20]  = B0.w;
    L[rb + 4 * 20]  = B1.x; L[rb + 5 * 20]  = B1.y; L[rb + 6 * 20]  = B1.z; L[rb + 7 * 20]  = B1.w;
    L[rb + 8 * 20]  = B2.x; L[rb + 9 * 20]  = B2.y; L[rb + 10 * 20] = B2.z; L[rb + 11 * 20] = B2.w;
    L[rb + 12 * 20] = B3.x; L[rb + 13 * 20] = B3.y; L[rb + 14 * 20] = B3.z; L[rb + 15 * 20] = B3.w;
    __syncthreads();
    const int cb = (lane >> 2) * 20 + (lane & 3) * 4;
    f32x4 V0 = *(const f32x4*)(L + cb);         // b9=0,b8=0
    f32x4 V1 = *(const f32x4*)(L + cb + 320);   // b8=1
    f32x4 V2 = *(const f32x4*)(L + cb + 640);   // b9=1
    f32x4 V3 = *(const f32x4*)(L + cb + 960);   // b9=1,b8=1

    {   // stage 8: flip b8 -> (V0,V1), (V2,V3)
        f32x4 t0 = T[2048 + lane * 2], t1 = T[2048 + lane * 2 + 1];
        f32x4 t2 = T[2048 + 128 + lane * 2], t3 = T[2048 + 128 + lane * 2 + 1];
        ROT(V0.x, V1.x, t0.x, t0.y); ROT(V0.y, V1.y, t0.z, t0.w);
        ROT(V0.z, V1.z, t1.x, t1.y); ROT(V0.w, V1.w, t1.z, t1.w);
        ROT(V2.x, V3.x, t2.x, t2.y); ROT(V2.y, V3.y, t2.z, t2.w);
        ROT(V2.z, V3.z, t3.x, t3.y); ROT(V2.w, V3.w, t3.z, t3.w);
    }
    {   // stage 9: flip b9 -> (V0,V2), (V1,V3)
        f32x4 t0 = T[2304 + lane * 2], t1 = T[2304 + lane * 2 + 1];
        f32x4 t2 = T[2304 + 128 + lane * 2], t3 = T[2304 + 128 + lane * 2 + 1];
        ROT(V0.x, V2.x, t0.x, t0.y); ROT(V0.y, V2.y, t0.z, t0.w);
        ROT(V0.z, V2.z, t1.x, t1.y); ROT(V0.w, V2.w, t1.z, t1.w);
        ROT(V1.x, V3.x, t2.x, t2.y); ROT(V1.y, V3.y, t2.z, t2.w);
        ROT(V1.z, V3.z, t3.x, t3.y); ROT(V1.w, V3.w, t3.z, t3.w);
    }

    // ---- store, coalesced (lane stride 16B)
    __builtin_nontemporal_store(V0, (f32x4*)(orr + lane * 4));
    __builtin_nontemporal_store(V1, (f32x4*)(orr + 256 + lane * 4));
    __builtin_nontemporal_store(V2, (f32x4*)(orr + 512 + lane * 4));
    __builtin_nontemporal_store(V3, (f32x4*)(orr + 768 + lane * 4));
}

extern "C" void kernel_launch(void* const* d_in, const int* in_sizes, int n_in,
                              void* d_out, int out_size, void* d_ws, size_t ws_size,
                              hipStream_t stream) {
    const float* x      = (const float*)d_in[0];
    const float* angles = (const float*)d_in[1];
    float*       out    = (float*)d_out;
    float2*      cs     = (float2*)d_ws;  // 10*512*8 = 40960 bytes

    const int ncs = BF_STAGES * (BF_DIM / 2);
    bf_fill_cs<<<(ncs + 255) / 256, 256, 0, stream>>>(angles, cs, ncs);

    const int rows   = in_sizes[0] / BF_DIM;
    const int blocks = (rows + 3) / 4;  // 1 row per wave, 4 waves per block
    bf_butterfly<<<blocks, 256, 0, stream>>>(x, (const f32x4*)cs, out, rows);
}

// Round 6
// 142.412 us; speedup vs baseline: 2.2295x; 1.6796x over previous
//
#include <hip/hip_runtime.h>

typedef float f32x4 __attribute__((ext_vector_type(4)));

#define BF_DIM 1024
#define BF_STAGES 10

// Tables: cs[s*512 + pos] = (cos, sin) of angles[s][k].
// Stages 0-3, 8, 9: pos = k (natural).
// Stages 4-7: permuted so each lane's 8 needed entries are contiguous:
//   k = hi2*128 + j*16 + lo4  ->  pos = (hi2*16 + lo4)*8 + j
__global__ void bf_fill_cs(const float* __restrict__ angles, float2* __restrict__ cs, int n) {
    int i = blockIdx.x * blockDim.x + threadIdx.x;
    if (i >= n) return;
    int s = i >> 9, k = i & 511;
    float a = angles[i];
    float sv, cv;
    sincosf(a, &sv, &cv);
    int pos;
    if (s >= 4 && s < 8) {
        int hi2 = k >> 7, j = (k >> 4) & 7, lo4 = k & 15;
        pos = ((hi2 << 4) | lo4) * 8 + j;
    } else {
        pos = k;
    }
    cs[s * 512 + pos] = make_float2(cv, sv);
}

#define ROT(vi, vj, c, s) do { float _t = fmaf(-(s), (vj), (c)*(vi)); \
                               (vj) = fmaf((s), (vi), (c)*(vj)); (vi) = _t; } while (0)

#define STAGE_EVEN_INNER(A0,A1,A2,A3,c0,c1,c2,c3) do { \
    ROT(A0.x,A0.y,c0.x,c0.y); ROT(A0.z,A0.w,c0.z,c0.w); \
    ROT(A1.x,A1.y,c1.x,c1.y); ROT(A1.z,A1.w,c1.z,c1.w); \
    ROT(A2.x,A2.y,c2.x,c2.y); ROT(A2.z,A2.w,c2.z,c2.w); \
    ROT(A3.x,A3.y,c3.x,c3.y); ROT(A3.z,A3.w,c3.z,c3.w); } while (0)
#define STAGE_ODD_INNER(A0,A1,A2,A3,c0,c1,c2,c3) do { \
    ROT(A0.x,A0.z,c0.x,c0.y); ROT(A0.y,A0.w,c0.z,c0.w); \
    ROT(A1.x,A1.z,c1.x,c1.y); ROT(A1.y,A1.w,c1.z,c1.w); \
    ROT(A2.x,A2.z,c2.x,c2.y); ROT(A2.y,A2.w,c2.z,c2.w); \
    ROT(A3.x,A3.z,c3.x,c3.y); ROT(A3.y,A3.w,c3.z,c3.w); } while (0)
#define STAGE_PAIR01(A0,A1,A2,A3,c0,c1,c2,c3) do { \
    ROT(A0.x,A1.x,c0.x,c0.y); ROT(A0.y,A1.y,c0.z,c0.w); \
    ROT(A0.z,A1.z,c1.x,c1.y); ROT(A0.w,A1.w,c1.z,c1.w); \
    ROT(A2.x,A3.x,c2.x,c2.y); ROT(A2.y,A3.y,c2.z,c2.w); \
    ROT(A2.z,A3.z,c3.x,c3.y); ROT(A2.w,A3.w,c3.z,c3.w); } while (0)
#define STAGE_PAIR02(A0,A1,A2,A3,c0,c1,c2,c3) do { \
    ROT(A0.x,A2.x,c0.x,c0.y); ROT(A0.y,A2.y,c0.z,c0.w); \
    ROT(A0.z,A2.z,c1.x,c1.y); ROT(A0.w,A2.w,c1.z,c1.w); \
    ROT(A1.x,A3.x,c2.x,c2.y); ROT(A1.y,A3.y,c2.z,c2.w); \
    ROT(A1.z,A3.z,c3.x,c3.y); ROT(A1.w,A3.w,c3.z,c3.w); } while (0)

// One wave = one row per loop iteration, 16 elems/thread, ZERO barriers:
// the LDS slab L is wave-private, and DS ops of a single wave execute in
// program order (lgkmcnt covers dependencies) -> __syncthreads is not needed.
// Round-5 lesson: the 3 barriers phase-locked all resident waves so the
// HBM / LDS / VALU / table phases ADDED (~240us) instead of overlapping.
// Grid-stride loop + 1-row-deep global prefetch hides HBM latency.
__global__ __launch_bounds__(256) void bf_butterfly(const float* __restrict__ x,
                                                    const f32x4* __restrict__ T,
                                                    float* __restrict__ out,
                                                    int n_rows, int row_stride) {
    __shared__ __align__(16) float lds[4 * 1280];  // 4 waves * 64 lanes * 20 words
    const int lane = threadIdx.x & 63;
    const int wv   = threadIdx.x >> 6;
    float* L = lds + wv * 1280;

    const int ta = lane * 4;                          // table slice (f32x4 idx)
    const int rb = (lane >> 4) * 320 + (lane & 15);   // layout B base
    const int cb = (lane >> 2) * 20 + (lane & 3) * 4; // layout C base
    const int wb = lane * 20;                         // layout A base

    int row = blockIdx.x * 4 + wv;
    if (row >= n_rows) return;

    // prime the software pipeline: prefetch row's data
    const float* xp = x + (long long)row * BF_DIM + lane * 16;
    f32x4 P0 = __builtin_nontemporal_load((const f32x4*)(xp + 0));
    f32x4 P1 = __builtin_nontemporal_load((const f32x4*)(xp + 4));
    f32x4 P2 = __builtin_nontemporal_load((const f32x4*)(xp + 8));
    f32x4 P3 = __builtin_nontemporal_load((const f32x4*)(xp + 12));

#pragma unroll 1
    while (true) {
        f32x4 U0 = P0, U1 = P1, U2 = P2, U3 = P3;

        // issue next row's loads now; consumed next iteration
        const int nxt = row + row_stride;
        const bool more = nxt < n_rows;
        const int pre = more ? nxt : row;
        xp = x + (long long)pre * BF_DIM + lane * 16;
        P0 = __builtin_nontemporal_load((const f32x4*)(xp + 0));
        P1 = __builtin_nontemporal_load((const f32x4*)(xp + 4));
        P2 = __builtin_nontemporal_load((const f32x4*)(xp + 8));
        P3 = __builtin_nontemporal_load((const f32x4*)(xp + 12));

        {   // stage 0
            f32x4 c0 = T[ta], c1 = T[ta + 1], c2 = T[ta + 2], c3 = T[ta + 3];
            STAGE_EVEN_INNER(U0, U1, U2, U3, c0, c1, c2, c3);
        }
        {   // stage 1
            f32x4 c0 = T[256 + ta], c1 = T[256 + ta + 1], c2 = T[256 + ta + 2], c3 = T[256 + ta + 3];
            STAGE_ODD_INNER(U0, U1, U2, U3, c0, c1, c2, c3);
        }
        {   // stage 2
            f32x4 c0 = T[512 + ta], c1 = T[512 + ta + 1], c2 = T[512 + ta + 2], c3 = T[512 + ta + 3];
            STAGE_PAIR01(U0, U1, U2, U3, c0, c1, c2, c3);
        }
        {   // stage 3
            f32x4 c0 = T[768 + ta], c1 = T[768 + ta + 1], c2 = T[768 + ta + 2], c3 = T[768 + ta + 3];
            STAGE_PAIR02(U0, U1, U2, U3, c0, c1, c2, c3);
        }

        // transpose 1: write layout A (b128), read layout B (b32). Wave-private.
        *(f32x4*)(L + wb + 0)  = U0;
        *(f32x4*)(L + wb + 4)  = U1;
        *(f32x4*)(L + wb + 8)  = U2;
        *(f32x4*)(L + wb + 12) = U3;
        f32x4 B0, B1, B2, B3;
        B0.x = L[rb + 0 * 20];  B0.y = L[rb + 1 * 20];  B0.z = L[rb + 2 * 20];  B0.w = L[rb + 3 * 20];
        B1.x = L[rb + 4 * 20];  B1.y = L[rb + 5 * 20];  B1.z = L[rb + 6 * 20];  B1.w = L[rb + 7 * 20];
        B2.x = L[rb + 8 * 20];  B2.y = L[rb + 9 * 20];  B2.z = L[rb + 10 * 20]; B2.w = L[rb + 11 * 20];
        B3.x = L[rb + 12 * 20]; B3.y = L[rb + 13 * 20]; B3.z = L[rb + 14 * 20]; B3.w = L[rb + 15 * 20];

        {   // stage 4
            f32x4 c0 = T[1024 + ta], c1 = T[1024 + ta + 1], c2 = T[1024 + ta + 2], c3 = T[1024 + ta + 3];
            STAGE_EVEN_INNER(B0, B1, B2, B3, c0, c1, c2, c3);
        }
        {   // stage 5
            f32x4 c0 = T[1280 + ta], c1 = T[1280 + ta + 1], c2 = T[1280 + ta + 2], c3 = T[1280 + ta + 3];
            STAGE_ODD_INNER(B0, B1, B2, B3, c0, c1, c2, c3);
        }
        {   // stage 6
            f32x4 c0 = T[1536 + ta], c1 = T[1536 + ta + 1], c2 = T[1536 + ta + 2], c3 = T[1536 + ta + 3];
            STAGE_PAIR01(B0, B1, B2, B3, c0, c1, c2, c3);
        }
        {   // stage 7
            f32x4 c0 = T[1792 + ta], c1 = T[1792 + ta + 1], c2 = T[1792 + ta + 2], c3 = T[1792 + ta + 3];
            STAGE_PAIR02(B0, B1, B2, B3, c0, c1, c2, c3);
        }

        // transpose 2: write layout B back (b32), read layout C (b128).
        // Stage 4-7 FMAs consumed the B-reads (lgkmcnt waited) before these
        // writes issue; same-wave DS ops are pipe-ordered -> no barrier.
        L[rb + 0 * 20]  = B0.x; L[rb + 1 * 20]  = B0.y; L[rb + 2 * 20]  = B0.z; L[rb + 3 * 20]  = B0.w;
        L[rb + 4 * 20]  = B1.x; L[rb + 5 * 20]  = B1.y; L[rb + 6 * 20]  = B1.z; L[rb + 7 * 20]  = B1.w;
        L[rb + 8 * 20]  = B2.x; L[rb + 9 * 20]  = B2.y; L[rb + 10 * 20] = B2.z; L[rb + 11 * 20] = B2.w;
        L[rb + 12 * 20] = B3.x; L[rb + 13 * 20] = B3.y; L[rb + 14 * 20] = B3.z; L[rb + 15 * 20] = B3.w;
        f32x4 V0 = *(const f32x4*)(L + cb);
        f32x4 V1 = *(const f32x4*)(L + cb + 320);
        f32x4 V2 = *(const f32x4*)(L + cb + 640);
        f32x4 V3 = *(const f32x4*)(L + cb + 960);

        {   // stage 8: (V0,V1), (V2,V3)
            f32x4 t0 = T[2048 + lane * 2], t1 = T[2048 + lane * 2 + 1];
            f32x4 t2 = T[2048 + 128 + lane * 2], t3 = T[2048 + 128 + lane * 2 + 1];
            ROT(V0.x, V1.x, t0.x, t0.y); ROT(V0.y, V1.y, t0.z, t0.w);
            ROT(V0.z, V1.z, t1.x, t1.y); ROT(V0.w, V1.w, t1.z, t1.w);
            ROT(V2.x, V3.x, t2.x, t2.y); ROT(V2.y, V3.y, t2.z, t2.w);
            ROT(V2.z, V3.z, t3.x, t3.y); ROT(V2.w, V3.w, t3.z, t3.w);
        }
        {   // stage 9: (V0,V2), (V1,V3)
            f32x4 t0 = T[2304 + lane * 2], t1 = T[2304 + lane * 2 + 1];
            f32x4 t2 = T[2304 + 128 + lane * 2], t3 = T[2304 + 128 + lane * 2 + 1];
            ROT(V0.x, V2.x, t0.x, t0.y); ROT(V0.y, V2.y, t0.z, t0.w);
            ROT(V0.z, V2.z, t1.x, t1.y); ROT(V0.w, V2.w, t1.z, t1.w);
            ROT(V1.x, V3.x, t2.x, t2.y); ROT(V1.y, V3.y, t2.z, t2.w);
            ROT(V1.z, V3.z, t3.x, t3.y); ROT(V1.w, V3.w, t3.z, t3.w);
        }

        float* orr = out + (long long)row * BF_DIM;
        __builtin_nontemporal_store(V0, (f32x4*)(orr + lane * 4));
        __builtin_nontemporal_store(V1, (f32x4*)(orr + 256 + lane * 4));
        __builtin_nontemporal_store(V2, (f32x4*)(orr + 512 + lane * 4));
        __builtin_nontemporal_store(V3, (f32x4*)(orr + 768 + lane * 4));

        if (!more) break;
        row = nxt;
    }
}

extern "C" void kernel_launch(void* const* d_in, const int* in_sizes, int n_in,
                              void* d_out, int out_size, void* d_ws, size_t ws_size,
                              hipStream_t stream) {
    const float* x      = (const float*)d_in[0];
    const float* angles = (const float*)d_in[1];
    float*       out    = (float*)d_out;
    float2*      cs     = (float2*)d_ws;  // 10*512*8 = 40960 bytes

    const int ncs = BF_STAGES * (BF_DIM / 2);
    bf_fill_cs<<<(ncs + 255) / 256, 256, 0, stream>>>(angles, cs, ncs);

    const int rows = in_sizes[0] / BF_DIM;
    int blocks = (rows + 3) / 4;
    if (blocks > 2048) blocks = 2048;        // 8 blocks/CU (LDS-limited max), grid-stride the rest
    const int row_stride = blocks * 4;       // total waves
    bf_butterfly<<<blocks, 256, 0, stream>>>(x, (const f32x4*)cs, out, rows, row_stride);
}

// Round 7
// 135.944 us; speedup vs baseline: 2.3356x; 1.0476x over previous
//
#include <hip/hip_runtime.h>

typedef float f32x4 __attribute__((ext_vector_type(4)));

#define BF_DIM 1024
#define BF_STAGES 10

// Tables: cs[s*512 + pos] = (cos, sin) of angles[s][k].
// Stages 0-3, 8, 9: pos = k (natural).
// Stages 4-7: permuted so each lane's 8 needed entries are contiguous:
//   k = hi2*128 + j*16 + lo4  ->  pos = (hi2*16 + lo4)*8 + j
__global__ void bf_fill_cs(const float* __restrict__ angles, float2* __restrict__ cs, int n) {
    int i = blockIdx.x * blockDim.x + threadIdx.x;
    if (i >= n) return;
    int s = i >> 9, k = i & 511;
    float a = angles[i];
    float sv, cv;
    sincosf(a, &sv, &cv);
    int pos;
    if (s >= 4 && s < 8) {
        int hi2 = k >> 7, j = (k >> 4) & 7, lo4 = k & 15;
        pos = ((hi2 << 4) | lo4) * 8 + j;
    } else {
        pos = k;
    }
    cs[s * 512 + pos] = make_float2(cv, sv);
}

#define ROT(vi, vj, c, s) do { float _t = fmaf(-(s), (vj), (c)*(vi)); \
                               (vj) = fmaf((s), (vi), (c)*(vj)); (vi) = _t; } while (0)

#define STAGE_EVEN_INNER(A0,A1,A2,A3,c0,c1,c2,c3) do { \
    ROT(A0.x,A0.y,c0.x,c0.y); ROT(A0.z,A0.w,c0.z,c0.w); \
    ROT(A1.x,A1.y,c1.x,c1.y); ROT(A1.z,A1.w,c1.z,c1.w); \
    ROT(A2.x,A2.y,c2.x,c2.y); ROT(A2.z,A2.w,c2.z,c2.w); \
    ROT(A3.x,A3.y,c3.x,c3.y); ROT(A3.z,A3.w,c3.z,c3.w); } while (0)
#define STAGE_ODD_INNER(A0,A1,A2,A3,c0,c1,c2,c3) do { \
    ROT(A0.x,A0.z,c0.x,c0.y); ROT(A0.y,A0.w,c0.z,c0.w); \
    ROT(A1.x,A1.z,c1.x,c1.y); ROT(A1.y,A1.w,c1.z,c1.w); \
    ROT(A2.x,A2.z,c2.x,c2.y); ROT(A2.y,A2.w,c2.z,c2.w); \
    ROT(A3.x,A3.z,c3.x,c3.y); ROT(A3.y,A3.w,c3.z,c3.w); } while (0)
#define STAGE_PAIR01(A0,A1,A2,A3,c0,c1,c2,c3) do { \
    ROT(A0.x,A1.x,c0.x,c0.y); ROT(A0.y,A1.y,c0.z,c0.w); \
    ROT(A0.z,A1.z,c1.x,c1.y); ROT(A0.w,A1.w,c1.z,c1.w); \
    ROT(A2.x,A3.x,c2.x,c2.y); ROT(A2.y,A3.y,c2.z,c2.w); \
    ROT(A2.z,A3.z,c3.x,c3.y); ROT(A2.w,A3.w,c3.z,c3.w); } while (0)
#define STAGE_PAIR02(A0,A1,A2,A3,c0,c1,c2,c3) do { \
    ROT(A0.x,A2.x,c0.x,c0.y); ROT(A0.y,A2.y,c0.z,c0.w); \
    ROT(A0.z,A2.z,c1.x,c1.y); ROT(A0.w,A2.w,c1.z,c1.w); \
    ROT(A1.x,A3.x,c2.x,c2.y); ROT(A1.y,A3.y,c2.z,c2.w); \
    ROT(A1.z,A3.z,c3.x,c3.y); ROT(A1.w,A3.w,c3.z,c3.w); } while (0)

// One wave = TWO rows per loop iteration (R=2): every stage's 4 table vectors
// are loaded ONCE and applied to both rows -> table L1/L2 traffic halves
// (round-6 analysis: 40KB/row/wave table re-reads ~= the HBM stream itself).
// 16 data elems/thread/row, zero cross-lane shuffles, ZERO barriers (LDS slab
// is wave-private; same-wave DS ops are pipe-ordered, lgkmcnt covers deps).
// Register budget: 32 data + 16 table + addressing ~ 60 <= the 64-VGPR cap
// this toolchain enforces for 256-thread blocks (rounds 2-4 evidence).
__global__ __launch_bounds__(256) void bf_butterfly(const float* __restrict__ x,
                                                    const f32x4* __restrict__ T,
                                                    float* __restrict__ out,
                                                    int n_rows, int pair_stride) {
    __shared__ __align__(16) float lds[4 * 2560];  // 4 waves * 2 rows * 20*64 words = 40 KB
    const int lane = threadIdx.x & 63;
    const int wv   = threadIdx.x >> 6;
    float* LA = lds + wv * 2560;   // row 0 slab
    float* LB = LA + 1280;         // row 1 slab

    const int ta = lane * 4;                          // table slice (f32x4 idx)
    const int rb = (lane >> 4) * 320 + (lane & 15);   // layout B base
    const int cb = (lane >> 2) * 20 + (lane & 3) * 4; // layout C base
    const int wb = lane * 20;                         // layout A base

    const int n_pairs = (n_rows + 1) >> 1;

#pragma unroll 1
    for (int pair = blockIdx.x * 4 + wv; pair < n_pairs; pair += pair_stride) {
        const int r0 = pair * 2;
        const int r1 = r0 + 1;
        const bool has1 = (r1 < n_rows);

        const float* xr0 = x + (long long)r0 * BF_DIM + lane * 16;
        const float* xr1 = x + (long long)(has1 ? r1 : r0) * BF_DIM + lane * 16;
        f32x4 U0 = __builtin_nontemporal_load((const f32x4*)(xr0 + 0));
        f32x4 U1 = __builtin_nontemporal_load((const f32x4*)(xr0 + 4));
        f32x4 U2 = __builtin_nontemporal_load((const f32x4*)(xr0 + 8));
        f32x4 U3 = __builtin_nontemporal_load((const f32x4*)(xr0 + 12));
        f32x4 W0 = __builtin_nontemporal_load((const f32x4*)(xr1 + 0));
        f32x4 W1 = __builtin_nontemporal_load((const f32x4*)(xr1 + 4));
        f32x4 W2 = __builtin_nontemporal_load((const f32x4*)(xr1 + 8));
        f32x4 W3 = __builtin_nontemporal_load((const f32x4*)(xr1 + 12));

        {   // stage 0 (tables shared by both rows)
            f32x4 c0 = T[ta], c1 = T[ta + 1], c2 = T[ta + 2], c3 = T[ta + 3];
            STAGE_EVEN_INNER(U0, U1, U2, U3, c0, c1, c2, c3);
            STAGE_EVEN_INNER(W0, W1, W2, W3, c0, c1, c2, c3);
        }
        {   // stage 1
            f32x4 c0 = T[256 + ta], c1 = T[256 + ta + 1], c2 = T[256 + ta + 2], c3 = T[256 + ta + 3];
            STAGE_ODD_INNER(U0, U1, U2, U3, c0, c1, c2, c3);
            STAGE_ODD_INNER(W0, W1, W2, W3, c0, c1, c2, c3);
        }
        {   // stage 2
            f32x4 c0 = T[512 + ta], c1 = T[512 + ta + 1], c2 = T[512 + ta + 2], c3 = T[512 + ta + 3];
            STAGE_PAIR01(U0, U1, U2, U3, c0, c1, c2, c3);
            STAGE_PAIR01(W0, W1, W2, W3, c0, c1, c2, c3);
        }
        {   // stage 3
            f32x4 c0 = T[768 + ta], c1 = T[768 + ta + 1], c2 = T[768 + ta + 2], c3 = T[768 + ta + 3];
            STAGE_PAIR02(U0, U1, U2, U3, c0, c1, c2, c3);
            STAGE_PAIR02(W0, W1, W2, W3, c0, c1, c2, c3);
        }

        // transpose 1: write layout A (b128), read layout B (b32); wave-private
        *(f32x4*)(LA + wb + 0)  = U0;
        *(f32x4*)(LA + wb + 4)  = U1;
        *(f32x4*)(LA + wb + 8)  = U2;
        *(f32x4*)(LA + wb + 12) = U3;
        *(f32x4*)(LB + wb + 0)  = W0;
        *(f32x4*)(LB + wb + 4)  = W1;
        *(f32x4*)(LB + wb + 8)  = W2;
        *(f32x4*)(LB + wb + 12) = W3;
        U0.x = LA[rb + 0 * 20];  U0.y = LA[rb + 1 * 20];  U0.z = LA[rb + 2 * 20];  U0.w = LA[rb + 3 * 20];
        U1.x = LA[rb + 4 * 20];  U1.y = LA[rb + 5 * 20];  U1.z = LA[rb + 6 * 20];  U1.w = LA[rb + 7 * 20];
        U2.x = LA[rb + 8 * 20];  U2.y = LA[rb + 9 * 20];  U2.z = LA[rb + 10 * 20]; U2.w = LA[rb + 11 * 20];
        U3.x = LA[rb + 12 * 20]; U3.y = LA[rb + 13 * 20]; U3.z = LA[rb + 14 * 20]; U3.w = LA[rb + 15 * 20];
        W0.x = LB[rb + 0 * 20];  W0.y = LB[rb + 1 * 20];  W0.z = LB[rb + 2 * 20];  W0.w = LB[rb + 3 * 20];
        W1.x = LB[rb + 4 * 20];  W1.y = LB[rb + 5 * 20];  W1.z = LB[rb + 6 * 20];  W1.w = LB[rb + 7 * 20];
        W2.x = LB[rb + 8 * 20];  W2.y = LB[rb + 9 * 20];  W2.z = LB[rb + 10 * 20]; W2.w = LB[rb + 11 * 20];
        W3.x = LB[rb + 12 * 20]; W3.y = LB[rb + 13 * 20]; W3.z = LB[rb + 14 * 20]; W3.w = LB[rb + 15 * 20];

        {   // stage 4
            f32x4 c0 = T[1024 + ta], c1 = T[1024 + ta + 1], c2 = T[1024 + ta + 2], c3 = T[1024 + ta + 3];
            STAGE_EVEN_INNER(U0, U1, U2, U3, c0, c1, c2, c3);
            STAGE_EVEN_INNER(W0, W1, W2, W3, c0, c1, c2, c3);
        }
        {   // stage 5
            f32x4 c0 = T[1280 + ta], c1 = T[1280 + ta + 1], c2 = T[1280 + ta + 2], c3 = T[1280 + ta + 3];
            STAGE_ODD_INNER(U0, U1, U2, U3, c0, c1, c2, c3);
            STAGE_ODD_INNER(W0, W1, W2, W3, c0, c1, c2, c3);
        }
        {   // stage 6
            f32x4 c0 = T[1536 + ta], c1 = T[1536 + ta + 1], c2 = T[1536 + ta + 2], c3 = T[1536 + ta + 3];
            STAGE_PAIR01(U0, U1, U2, U3, c0, c1, c2, c3);
            STAGE_PAIR01(W0, W1, W2, W3, c0, c1, c2, c3);
        }
        {   // stage 7
            f32x4 c0 = T[1792 + ta], c1 = T[1792 + ta + 1], c2 = T[1792 + ta + 2], c3 = T[1792 + ta + 3];
            STAGE_PAIR02(U0, U1, U2, U3, c0, c1, c2, c3);
            STAGE_PAIR02(W0, W1, W2, W3, c0, c1, c2, c3);
        }

        // transpose 2: write layout B back (b32), read layout C (b128).
        // Stage 4-7 FMAs consumed the B-reads before these writes issue;
        // same-wave DS ops are pipe-ordered -> no barrier.
        LA[rb + 0 * 20]  = U0.x; LA[rb + 1 * 20]  = U0.y; LA[rb + 2 * 20]  = U0.z; LA[rb + 3 * 20]  = U0.w;
        LA[rb + 4 * 20]  = U1.x; LA[rb + 5 * 20]  = U1.y; LA[rb + 6 * 20]  = U1.z; LA[rb + 7 * 20]  = U1.w;
        LA[rb + 8 * 20]  = U2.x; LA[rb + 9 * 20]  = U2.y; LA[rb + 10 * 20] = U2.z; LA[rb + 11 * 20] = U2.w;
        LA[rb + 12 * 20] = U3.x; LA[rb + 13 * 20] = U3.y; LA[rb + 14 * 20] = U3.z; LA[rb + 15 * 20] = U3.w;
        LB[rb + 0 * 20]  = W0.x; LB[rb + 1 * 20]  = W0.y; LB[rb + 2 * 20]  = W0.z; LB[rb + 3 * 20]  = W0.w;
        LB[rb + 4 * 20]  = W1.x; LB[rb + 5 * 20]  = W1.y; LB[rb + 6 * 20]  = W1.z; LB[rb + 7 * 20]  = W1.w;
        LB[rb + 8 * 20]  = W2.x; LB[rb + 9 * 20]  = W2.y; LB[rb + 10 * 20] = W2.z; LB[rb + 11 * 20] = W2.w;
        LB[rb + 12 * 20] = W3.x; LB[rb + 13 * 20] = W3.y; LB[rb + 14 * 20] = W3.z; LB[rb + 15 * 20] = W3.w;
        U0 = *(const f32x4*)(LA + cb);
        U1 = *(const f32x4*)(LA + cb + 320);
        U2 = *(const f32x4*)(LA + cb + 640);
        U3 = *(const f32x4*)(LA + cb + 960);
        W0 = *(const f32x4*)(LB + cb);
        W1 = *(const f32x4*)(LB + cb + 320);
        W2 = *(const f32x4*)(LB + cb + 640);
        W3 = *(const f32x4*)(LB + cb + 960);

        {   // stage 8: (0,1), (2,3)
            f32x4 t0 = T[2048 + lane * 2], t1 = T[2048 + lane * 2 + 1];
            f32x4 t2 = T[2048 + 128 + lane * 2], t3 = T[2048 + 128 + lane * 2 + 1];
            ROT(U0.x, U1.x, t0.x, t0.y); ROT(U0.y, U1.y, t0.z, t0.w);
            ROT(U0.z, U1.z, t1.x, t1.y); ROT(U0.w, U1.w, t1.z, t1.w);
            ROT(U2.x, U3.x, t2.x, t2.y); ROT(U2.y, U3.y, t2.z, t2.w);
            ROT(U2.z, U3.z, t3.x, t3.y); ROT(U2.w, U3.w, t3.z, t3.w);
            ROT(W0.x, W1.x, t0.x, t0.y); ROT(W0.y, W1.y, t0.z, t0.w);
            ROT(W0.z, W1.z, t1.x, t1.y); ROT(W0.w, W1.w, t1.z, t1.w);
            ROT(W2.x, W3.x, t2.x, t2.y); ROT(W2.y, W3.y, t2.z, t2.w);
            ROT(W2.z, W3.z, t3.x, t3.y); ROT(W2.w, W3.w, t3.z, t3.w);
        }
        {   // stage 9: (0,2), (1,3)
            f32x4 t0 = T[2304 + lane * 2], t1 = T[2304 + lane * 2 + 1];
            f32x4 t2 = T[2304 + 128 + lane * 2], t3 = T[2304 + 128 + lane * 2 + 1];
            ROT(U0.x, U2.x, t0.x, t0.y); ROT(U0.y, U2.y, t0.z, t0.w);
            ROT(U0.z, U2.z, t1.x, t1.y); ROT(U0.w, U2.w, t1.z, t1.w);
            ROT(U1.x, U3.x, t2.x, t2.y); ROT(U1.y, U3.y, t2.z, t2.w);
            ROT(U1.z, U3.z, t3.x, t3.y); ROT(U1.w, U3.w, t3.z, t3.w);
            ROT(W0.x, W2.x, t0.x, t0.y); ROT(W0.y, W2.y, t0.z, t0.w);
            ROT(W0.z, W2.z, t1.x, t1.y); ROT(W0.w, W2.w, t1.z, t1.w);
            ROT(W1.x, W3.x, t2.x, t2.y); ROT(W1.y, W3.y, t2.z, t2.w);
            ROT(W1.z, W3.z, t3.x, t3.y); ROT(W1.w, W3.w, t3.z, t3.w);
        }

        float* o0 = out + (long long)r0 * BF_DIM;
        __builtin_nontemporal_store(U0, (f32x4*)(o0 + lane * 4));
        __builtin_nontemporal_store(U1, (f32x4*)(o0 + 256 + lane * 4));
        __builtin_nontemporal_store(U2, (f32x4*)(o0 + 512 + lane * 4));
        __builtin_nontemporal_store(U3, (f32x4*)(o0 + 768 + lane * 4));
        if (has1) {
            float* o1 = out + (long long)r1 * BF_DIM;
            __builtin_nontemporal_store(W0, (f32x4*)(o1 + lane * 4));
            __builtin_nontemporal_store(W1, (f32x4*)(o1 + 256 + lane * 4));
            __builtin_nontemporal_store(W2, (f32x4*)(o1 + 512 + lane * 4));
            __builtin_nontemporal_store(W3, (f32x4*)(o1 + 768 + lane * 4));
        }
    }
}

extern "C" void kernel_launch(void* const* d_in, const int* in_sizes, int n_in,
                              void* d_out, int out_size, void* d_ws, size_t ws_size,
                              hipStream_t stream) {
    const float* x      = (const float*)d_in[0];
    const float* angles = (const float*)d_in[1];
    float*       out    = (float*)d_out;
    float2*      cs     = (float2*)d_ws;  // 10*512*8 = 40960 bytes

    const int ncs = BF_STAGES * (BF_DIM / 2);
    bf_fill_cs<<<(ncs + 255) / 256, 256, 0, stream>>>(angles, cs, ncs);

    const int rows    = in_sizes[0] / BF_DIM;
    const int n_pairs = (rows + 1) / 2;
    int blocks = (n_pairs + 3) / 4;
    if (blocks > 1024) blocks = 1024;     // 4 blocks/CU (40KB LDS) exactly resident
    const int pair_stride = blocks * 4;   // total waves
    bf_butterfly<<<blocks, 256, 0, stream>>>(x, (const f32x4*)cs, out, rows, pair_stride);
}